// Round 6
// baseline (242.025 us; speedup 1.0000x reference)
//
#include <hip/hip_runtime.h>

#define N_PTS 8192
#define D_DIM 256
#define BN 256              // set1 rows per block (n)
#define BM 128              // set2 rows per block (m)
#define BK 64
#define INF_BITS 0x7F800000u

typedef __attribute__((ext_vector_type(8))) short short8;
typedef __attribute__((ext_vector_type(4))) float f32x4;

__device__ unsigned g_cnt;   // last-block-done counter (reset by prep each launch)

// async global->LDS, 16B/lane; LDS dest = wave-uniform base + lane*16
__device__ __forceinline__ void gload_lds16(const ushort* g, ushort* l) {
    __builtin_amdgcn_global_load_lds(
        (const __attribute__((address_space(1))) void*)g,
        (__attribute__((address_space(3))) void*)l, 16, 0, 0);
}

__device__ __forceinline__ ushort f2bf(float x) {
    unsigned u = __float_as_uint(x);
    return (ushort)((u + 0x7FFFu + ((u >> 16) & 1u)) >> 16);  // RNE, no NaNs here
}

// ---- prep: pack to 16-row fragment-major (matches 16x16x32 frag) + sqnorms ----
// Packed16 layout: grp = row>>4, kb = k>>5; chunk (grp,kb) = 512 shorts where
// lane dl = (row&15) + 16*q holds 8 bf16 of row (dl&15) at k = kb*32 + q*8.
// Offset (shorts) = grp*4096 + kb*512 + dl*8. A 16x16x32 MFMA fragment is then
// ONE contiguous 1KB chunk in exact lane order.
__global__ __launch_bounds__(256) void prep_kernel(
        const float* __restrict__ s1, const float* __restrict__ s2,
        ushort* __restrict__ p1, ushort* __restrict__ p2,
        float* __restrict__ sq1, float* __restrict__ sq2,
        unsigned* __restrict__ rowmin2, unsigned* __restrict__ colmin2) {
    const int pg = blockIdx.x;                  // 512 blocks = 512 32-row panels
    if (pg == 0 && threadIdx.x == 0) atomicExch(&g_cnt, 0u);
    const bool first = pg < 256;
    const int p = first ? pg : pg - 256;
    const float* src = first ? s1 : s2;
    ushort* dst = first ? p1 : p2;
    const int tid = threadIdx.x, sg = tid >> 6, lane = tid & 63;
    const int hi = lane >> 5, l31 = lane & 31;
    // wave sg covers 16-k slices sl = sg*4..+3; lane holds row p*32+l31, k=sl*16+hi*8
    const float* rowp = src + (size_t)(p * 32 + l31) * D_DIM + sg * 64 + hi * 8;
    float s = 0.f;
    #pragma unroll
    for (int sl = 0; sl < 4; ++sl) {
        float4 v0 = *(const float4*)(rowp + sl * 16);
        float4 v1 = *(const float4*)(rowp + sl * 16 + 4);
        s += v0.x * v0.x + v0.y * v0.y + v0.z * v0.z + v0.w * v0.w
           + v1.x * v1.x + v1.y * v1.y + v1.z * v1.z + v1.w * v1.w;
        ushort4 o0 = { f2bf(v0.x), f2bf(v0.y), f2bf(v0.z), f2bf(v0.w) };
        ushort4 o1 = { f2bf(v1.x), f2bf(v1.y), f2bf(v1.z), f2bf(v1.w) };
        // dest: grp = p*2 + (l31>>4); kb = (sg*4+sl)>>1; q = ((sl&1)*2 + hi)
        const int sla = sg * 4 + sl;
        ushort* outp = dst + (size_t)(p * 2 + (l31 >> 4)) * 4096
                     + (sla >> 1) * 512
                     + ((l31 & 15) + 16 * ((sla & 1) * 2 + hi)) * 8;
        *(ushort4*)(outp)     = o0;
        *(ushort4*)(outp + 4) = o1;
    }
    s += __shfl_xor(s, 32, 64);                 // combine the two k-halves
    __shared__ float part[4][32];
    if (hi == 0) part[sg][l31] = s;
    __syncthreads();
    if (tid < 32) {
        float tot = part[0][tid] + part[1][tid] + part[2][tid] + part[3][tid];
        (first ? sq1 : sq2)[p * 32 + tid] = tot;
        (first ? rowmin2 : colmin2)[p * 32 + tid] = INF_BITS;
    }
}

// ---- tile: R0's EXACT schedule/shape/acc/epilogue, packed16 operand path ----
// Per K-tile: 12 contiguous-1KB gload_lds per wave, sync, 2 kk-slices of
// {12 stride-1 ds_read_b128 (wave-uniform base + lane*16, zero addr VALU)
// + 32 MFMA 16x16x32}, sync. acc = f32x4[8][4] (R0's proven codegen).
__global__ __launch_bounds__(256, 2) void tile_kernel(
    const ushort* __restrict__ P1, const ushort* __restrict__ P2,
    const float* __restrict__ sq1, const float* __restrict__ sq2,
    unsigned* __restrict__ rowmin2, unsigned* __restrict__ colmin2,
    float* __restrict__ out) {
    __shared__ ushort As[16 * 2 * 512] __attribute__((aligned(16)));  // 32 KB: [grp16][kb2][512]
    __shared__ ushort Bs[ 8 * 2 * 512] __attribute__((aligned(16)));  // 16 KB
    __shared__ unsigned rs[BN];
    __shared__ unsigned cs[BM];
    __shared__ float wsum[4];
    __shared__ unsigned lastf;

    const int tid  = threadIdx.x;
    const int lane = tid & 63;
    const int w    = tid >> 6;          // 4 waves: 2 (n) x 2 (m)
    const int quad = lane >> 4;
    const int c    = lane & 15;
    const int n_off = (w >> 1) * 128;   // wave tile: 128(n) x 64(m)
    const int m_off = (w & 1) * 64;
    const int n0 = blockIdx.y * BN;
    const int m0 = blockIdx.x * BM;

    rs[tid] = INF_BITS;
    if (tid < BM) cs[tid] = INF_BITS;

    f32x4 acc[8][4];
    #pragma unroll
    for (int ti = 0; ti < 8; ti++)
        #pragma unroll
        for (int tj = 0; tj < 4; tj++) acc[ti][tj] = (f32x4){0.f, 0.f, 0.f, 0.f};

    // packed sources: grp stride 4096 shorts, kb stride 512
    const ushort* gA = P1 + (size_t)(n0 >> 4) * 4096 + lane * 8;
    const ushort* gB = P2 + (size_t)(m0 >> 4) * 4096 + lane * 8;

    #pragma unroll
    for (int t = 0; t < D_DIM / BK; ++t) {      // 4 K-tiles of 64 (kb pair)
        // As: 16 grps x 2 kbs = 32 chunks, 8 rounds of 4 waves
        #pragma unroll
        for (int r = 0; r < 8; r++) {
            int ch = r * 4 + w;                 // g = ch>>1, kb_local = ch&1
            gload_lds16(gA + (size_t)(ch >> 1) * 4096 + (t * 2 + (ch & 1)) * 512,
                        &As[ch * 512]);
        }
        // Bs: 8 grps x 2 kbs = 16 chunks, 4 rounds
        #pragma unroll
        for (int r = 0; r < 4; r++) {
            int ch = r * 4 + w;
            gload_lds16(gB + (size_t)(ch >> 1) * 4096 + (t * 2 + (ch & 1)) * 512,
                        &Bs[ch * 512]);
        }
        __syncthreads();                        // stage drained

        #pragma unroll
        for (int kk = 0; kk < 2; kk++) {
            short8 a[8], b[4];
            #pragma unroll
            for (int ti = 0; ti < 8; ti++)
                a[ti] = *(const short8*)&As[(((n_off >> 4) + ti) * 2 + kk) * 512 + lane * 8];
            #pragma unroll
            for (int tj = 0; tj < 4; tj++)
                b[tj] = *(const short8*)&Bs[(((m_off >> 4) + tj) * 2 + kk) * 512 + lane * 8];
            #pragma unroll
            for (int ti = 0; ti < 8; ti++)
                #pragma unroll
                for (int tj = 0; tj < 4; tj++)
                    acc[ti][tj] = __builtin_amdgcn_mfma_f32_16x16x32_bf16(
                        a[ti], b[tj], acc[ti][tj], 0, 0, 0);
        }
        __syncthreads();
    }

    // epilogue (R0-verified): d2 = sq1[n]+sq2[m]-2*gram; C/D: col(m)=lane&15, row(n)=quad*4+reg
    float sqm[4];
    #pragma unroll
    for (int tj = 0; tj < 4; tj++) sqm[tj] = sq2[m0 + m_off + tj * 16 + c];
    float cmin[4];
    #pragma unroll
    for (int tj = 0; tj < 4; tj++) cmin[tj] = __uint_as_float(INF_BITS);

    #pragma unroll
    for (int ti = 0; ti < 8; ti++) {
        float4 sqn = *(const float4*)&sq1[n0 + n_off + ti * 16 + quad * 4];
        float rmin[4] = { __uint_as_float(INF_BITS), __uint_as_float(INF_BITS),
                          __uint_as_float(INF_BITS), __uint_as_float(INF_BITS) };
        #pragma unroll
        for (int tj = 0; tj < 4; tj++) {
            float sn[4] = { sqn.x, sqn.y, sqn.z, sqn.w };
            #pragma unroll
            for (int r = 0; r < 4; r++) {
                float d2 = fmaxf(sn[r] + sqm[tj] - 2.f * acc[ti][tj][r], 0.f);
                rmin[r]  = fminf(rmin[r], d2);
                cmin[tj] = fminf(cmin[tj], d2);
            }
        }
        // reduce row-mins over the 16 lanes (c) of the quad
        #pragma unroll
        for (int m = 1; m <= 8; m <<= 1)
            #pragma unroll
            for (int r = 0; r < 4; r++)
                rmin[r] = fminf(rmin[r], __shfl_xor(rmin[r], m, 64));
        if (c == 0) {
            #pragma unroll
            for (int r = 0; r < 4; r++)
                atomicMin(&rs[n_off + ti * 16 + quad * 4 + r], __float_as_uint(rmin[r]));
        }
    }
    // reduce col-mins over the 4 quads
    #pragma unroll
    for (int m = 16; m <= 32; m <<= 1)
        #pragma unroll
        for (int tj = 0; tj < 4; tj++)
            cmin[tj] = fminf(cmin[tj], __shfl_xor(cmin[tj], m, 64));
    if (quad == 0) {
        #pragma unroll
        for (int tj = 0; tj < 4; tj++)
            atomicMin(&cs[m_off + tj * 16 + c], __float_as_uint(cmin[tj]));
    }
    __syncthreads();

    atomicMin(&rowmin2[n0 + tid], rs[tid]);          // BN == 256 == blockDim
    if (tid < BM) atomicMin(&colmin2[m0 + tid], cs[tid]);

    // ---- fused final reduce (R3/R4/R5-verified): last block -> mean(sqrt) ----
    __threadfence();
    if (tid == 0)
        lastf = (atomicAdd(&g_cnt, 1u) == (unsigned)(gridDim.x * gridDim.y - 1));
    __syncthreads();
    if (lastf) {
        float s = 0.f;
        #pragma unroll 8
        for (int j = 0; j < 64; ++j) {           // rowmin2||colmin2 contiguous 16384
            unsigned u = __hip_atomic_load(&rowmin2[tid + 256 * j],
                                           __ATOMIC_RELAXED, __HIP_MEMORY_SCOPE_AGENT);
            s += sqrtf(__uint_as_float(u));
        }
        #pragma unroll
        for (int m = 1; m <= 32; m <<= 1) s += __shfl_xor(s, m, 64);
        if (lane == 0) wsum[w] = s;
        __syncthreads();
        if (tid == 0) out[0] = (wsum[0] + wsum[1] + wsum[2] + wsum[3]) / (float)N_PTS;
    }
}

extern "C" void kernel_launch(void* const* d_in, const int* in_sizes, int n_in,
                              void* d_out, int out_size, void* d_ws, size_t ws_size,
                              hipStream_t stream) {
    const float* set1 = (const float*)d_in[0];
    const float* set2 = (const float*)d_in[1];
    float* out = (float*)d_out;

    // workspace: rowmin2[8192] | colmin2[8192] (contiguous!) | sq1 | sq2 | p1 | p2
    unsigned* rowmin2 = (unsigned*)d_ws;
    unsigned* colmin2 = rowmin2 + N_PTS;
    float* sq1 = (float*)(colmin2 + N_PTS);
    float* sq2 = sq1 + N_PTS;
    ushort* p1 = (ushort*)((char*)d_ws + 128 * 1024);       // 256B-aligned, past headers
    ushort* p2 = p1 + (size_t)N_PTS * D_DIM;

    prep_kernel<<<512, 256, 0, stream>>>(
        set1, set2, p1, p2, sq1, sq2, rowmin2, colmin2);
    tile_kernel<<<dim3(N_PTS / BM, N_PTS / BN), 256, 0, stream>>>(
        p1, p2, sq1, sq2, rowmin2, colmin2, out);
}

// Round 7
// 118.296 us; speedup vs baseline: 2.0459x; 2.0459x over previous
//
#include <hip/hip_runtime.h>

#define N_PTS 8192
#define D_DIM 256
#define BN 256              // set1 rows per block
#define BM 128              // set2 rows per block
#define BK 64
#define INF_BITS 0x7F800000u

typedef __attribute__((ext_vector_type(8))) short short8;
typedef __attribute__((ext_vector_type(4))) float f32x4;

// async global->LDS, 16B/lane; LDS dest = wave-uniform base + lane*16
__device__ __forceinline__ void gload_lds16(const ushort* g, ushort* l) {
    __builtin_amdgcn_global_load_lds(
        (const __attribute__((address_space(1))) void*)g,
        (__attribute__((address_space(3))) void*)l, 16, 0, 0);
}

__device__ __forceinline__ ushort f2bf(float x) {
    unsigned u = __float_as_uint(x);
    return (ushort)((u + 0x7FFFu + ((u >> 16) & 1u)) >> 16);  // RNE, no NaNs here
}

// ---- fused prep: bf16 convert + row sqnorms (fp32 exact) + INF init ----
__global__ void prep_kernel(const float* __restrict__ s1, const float* __restrict__ s2,
                            ushort* __restrict__ b1, ushort* __restrict__ b2,
                            float* __restrict__ sq1, float* __restrict__ sq2,
                            unsigned* __restrict__ rowmin2, unsigned* __restrict__ colmin2) {
    const int half = N_PTS * D_DIM;
    int t = blockIdx.x * 256 + threadIdx.x;
    int e = t * 8;
    bool first = e < half;
    const float* src = first ? s1 : s2;
    ushort* dst = first ? b1 : b2;
    int off = first ? e : e - half;
    float4 v0 = *(const float4*)(src + off);
    float4 v1 = *(const float4*)(src + off + 4);
    float s = v0.x * v0.x + v0.y * v0.y + v0.z * v0.z + v0.w * v0.w
            + v1.x * v1.x + v1.y * v1.y + v1.z * v1.z + v1.w * v1.w;
    ushort4 o0 = { f2bf(v0.x), f2bf(v0.y), f2bf(v0.z), f2bf(v0.w) };
    ushort4 o1 = { f2bf(v1.x), f2bf(v1.y), f2bf(v1.z), f2bf(v1.w) };
    *(ushort4*)(dst + off)     = o0;
    *(ushort4*)(dst + off + 4) = o1;
    // one row = 32 consecutive threads; xor masks <=16 stay inside the half-wave
    #pragma unroll
    for (int m = 1; m <= 16; m <<= 1) s += __shfl_xor(s, m, 64);
    int sub = threadIdx.x & 31;
    int row = off >> 8;
    if (sub == 0) (first ? sq1 : sq2)[row] = s;
    if (sub == 1) (first ? rowmin2 : colmin2)[row] = INF_BITS;
}

// ---- MFMA gram + fused d^2 + row/col min (R0-exact) + XCD-chunked swizzle ----
__global__ __launch_bounds__(256, 2) void tile_kernel(
    const ushort* __restrict__ B1, const ushort* __restrict__ B2,
    const float* __restrict__ sq1, const float* __restrict__ sq2,
    unsigned* __restrict__ rowmin2, unsigned* __restrict__ colmin2) {
    // unpadded row-major [rows][BK] bf16, XOR-swizzled in 16B chunks:
    // LDS slot (row, sc) holds global chunk (row, sc ^ (row&7))
    __shared__ ushort As[BN * BK] __attribute__((aligned(16)));   // 32 KB
    __shared__ ushort Bs[BM * BK] __attribute__((aligned(16)));   // 16 KB
    __shared__ unsigned rs[BN];
    __shared__ unsigned cs[BM];

    const int tid  = threadIdx.x;
    const int lane = tid & 63;
    const int w    = tid >> 6;
    const int quad = lane >> 4;
    const int c    = lane & 15;
    const int n_off = (w >> 1) * 128;   // wave tile: 128(n) x 64(m)
    const int m_off = (w & 1) * 64;

    // XCD-chunked bijective swizzle (T1; 2048 % 8 == 0): XCD k owns the 256
    // consecutive tiles covering n-rows [4k,4k+4) x all m -> per-XCD L2 keeps
    // 1-2 A-panels hot and B-panel L3 re-sweeps drop 8x vs default round-robin.
    unsigned bid = blockIdx.y * gridDim.x + blockIdx.x;   // gridDim = (64, 32)
    unsigned swz = (bid & 7) * 256 + (bid >> 3);
    const int m0 = (int)(swz & 63) * BM;
    const int n0 = (int)(swz >> 6) * BN;

    rs[tid] = INF_BITS;
    if (tid < BM) cs[tid] = INF_BITS;

    f32x4 acc[8][4];
    #pragma unroll
    for (int ti = 0; ti < 8; ti++)
        #pragma unroll
        for (int tj = 0; tj < 4; tj++) acc[ti][tj] = (f32x4){0.f, 0.f, 0.f, 0.f};

    for (int k0 = 0; k0 < D_DIM; k0 += BK) {
        // stage As: 256 rows x 8 chunks = 2048 chunks, 8 rounds of 256
        #pragma unroll
        for (int r = 0; r < 8; r++) {
            int idx = r * 256 + tid;
            int row = idx >> 3;
            int gc  = (idx & 7) ^ (row & 7);
            gload_lds16(B1 + (size_t)(n0 + row) * D_DIM + k0 + gc * 8,
                        &As[(idx & ~63) * 8]);
        }
        // stage Bs: 128 rows x 8 chunks = 1024 chunks, 4 rounds
        #pragma unroll
        for (int r = 0; r < 4; r++) {
            int idx = r * 256 + tid;
            int row = idx >> 3;
            int gc  = (idx & 7) ^ (row & 7);
            gload_lds16(B2 + (size_t)(m0 + row) * D_DIM + k0 + gc * 8,
                        &Bs[(idx & ~63) * 8]);
        }
        __syncthreads();

        #pragma unroll
        for (int kk = 0; kk < 2; kk++) {
            short8 a[8], b[4];
            #pragma unroll
            for (int ti = 0; ti < 8; ti++) {
                int row = n_off + ti * 16 + c;
                int ch  = (kk * 4 + quad) ^ (row & 7);
                a[ti] = *(const short8*)&As[row * BK + ch * 8];
            }
            #pragma unroll
            for (int tj = 0; tj < 4; tj++) {
                int row = m_off + tj * 16 + c;
                int ch  = (kk * 4 + quad) ^ (row & 7);
                b[tj] = *(const short8*)&Bs[row * BK + ch * 8];
            }
            #pragma unroll
            for (int ti = 0; ti < 8; ti++)
                #pragma unroll
                for (int tj = 0; tj < 4; tj++)
                    acc[ti][tj] = __builtin_amdgcn_mfma_f32_16x16x32_bf16(
                        a[ti], b[tj], acc[ti][tj], 0, 0, 0);
        }
        __syncthreads();
    }

    // epilogue: d2 = sq1[n]+sq2[m]-2*gram; C/D: col(m)=lane&15, row(n)=quad*4+reg
    float sqm[4];
    #pragma unroll
    for (int tj = 0; tj < 4; tj++) sqm[tj] = sq2[m0 + m_off + tj * 16 + c];
    float cmin[4];
    #pragma unroll
    for (int tj = 0; tj < 4; tj++) cmin[tj] = __uint_as_float(INF_BITS);

    #pragma unroll
    for (int ti = 0; ti < 8; ti++) {
        float4 sqn = *(const float4*)&sq1[n0 + n_off + ti * 16 + quad * 4];
        float rmin[4] = { __uint_as_float(INF_BITS), __uint_as_float(INF_BITS),
                          __uint_as_float(INF_BITS), __uint_as_float(INF_BITS) };
        #pragma unroll
        for (int tj = 0; tj < 4; tj++) {
            float sn[4] = { sqn.x, sqn.y, sqn.z, sqn.w };
            #pragma unroll
            for (int r = 0; r < 4; r++) {
                float d2 = fmaxf(sn[r] + sqm[tj] - 2.f * acc[ti][tj][r], 0.f);
                rmin[r]  = fminf(rmin[r], d2);
                cmin[tj] = fminf(cmin[tj], d2);
            }
        }
        // reduce row-mins over the 16 lanes (c) of the quad
        #pragma unroll
        for (int m = 1; m <= 8; m <<= 1)
            #pragma unroll
            for (int r = 0; r < 4; r++)
                rmin[r] = fminf(rmin[r], __shfl_xor(rmin[r], m, 64));
        if (c == 0) {
            #pragma unroll
            for (int r = 0; r < 4; r++)
                atomicMin(&rs[n_off + ti * 16 + quad * 4 + r], __float_as_uint(rmin[r]));
        }
    }
    // reduce col-mins over the 4 quads
    #pragma unroll
    for (int m = 16; m <= 32; m <<= 1)
        #pragma unroll
        for (int tj = 0; tj < 4; tj++)
            cmin[tj] = fminf(cmin[tj], __shfl_xor(cmin[tj], m, 64));
    if (quad == 0) {
        #pragma unroll
        for (int tj = 0; tj < 4; tj++)
            atomicMin(&cs[m_off + tj * 16 + c], __float_as_uint(cmin[tj]));
    }
    __syncthreads();

    atomicMin(&rowmin2[n0 + tid], rs[tid]);          // BN == 256 == blockDim
    if (tid < BM) atomicMin(&colmin2[m0 + tid], cs[tid]);
}

// ---- final: mean(sqrt(min d^2)) over rowmin2||colmin2 (contiguous 2*N_PTS) ----
__global__ __launch_bounds__(1024) void reduce_kernel(const unsigned* __restrict__ mins,
                                                      float* __restrict__ out) {
    int tid = threadIdx.x;
    uint4 v[4];
    #pragma unroll
    for (int j = 0; j < 4; j++) v[j] = ((const uint4*)mins)[j * 1024 + tid];
    float s = 0.f;
    #pragma unroll
    for (int j = 0; j < 4; j++)
        s += sqrtf(__uint_as_float(v[j].x)) + sqrtf(__uint_as_float(v[j].y))
           + sqrtf(__uint_as_float(v[j].z)) + sqrtf(__uint_as_float(v[j].w));
    #pragma unroll
    for (int m = 32; m > 0; m >>= 1) s += __shfl_xor(s, m, 64);
    __shared__ float ws[16];
    int lane = tid & 63, wv = tid >> 6;
    if (lane == 0) ws[wv] = s;
    __syncthreads();
    if (tid < 16) {
        float t = ws[tid];
        #pragma unroll
        for (int m = 8; m > 0; m >>= 1) t += __shfl_xor(t, m, 64);
        if (tid == 0) out[0] = t / (float)N_PTS;
    }
}

extern "C" void kernel_launch(void* const* d_in, const int* in_sizes, int n_in,
                              void* d_out, int out_size, void* d_ws, size_t ws_size,
                              hipStream_t stream) {
    const float* set1 = (const float*)d_in[0];
    const float* set2 = (const float*)d_in[1];
    float* out = (float*)d_out;

    // workspace: rowmin2[8192] | colmin2[8192] (contiguous!) | sq1 | sq2 | pad | b1 | b2
    unsigned* rowmin2 = (unsigned*)d_ws;
    unsigned* colmin2 = rowmin2 + N_PTS;
    float* sq1 = (float*)(colmin2 + N_PTS);
    float* sq2 = sq1 + N_PTS;
    ushort* b1 = (ushort*)((char*)d_ws + 128 * 1024);       // 256B-aligned, past headers
    ushort* b2 = b1 + (size_t)N_PTS * D_DIM;

    prep_kernel<<<(2 * N_PTS * D_DIM) / (256 * 8), 256, 0, stream>>>(
        set1, set2, b1, b2, sq1, sq2, rowmin2, colmin2);
    tile_kernel<<<dim3(N_PTS / BM, N_PTS / BN), 256, 0, stream>>>(
        b1, b2, sq1, sq2, rowmin2, colmin2);
    reduce_kernel<<<1, 1024, 0, stream>>>(rowmin2, out);
}